// Round 5
// baseline (124.404 us; speedup 1.0000x reference)
//
#include <hip/hip_runtime.h>
#include <math.h>

#define H      128
#define FCN    400
#define L1N    500
#define L2N    63
#define STEPS  65536
#define TPB    256

// ws float offsets (all written before read each launch; no memset needed)
#define WS_T    0        // T  [500][128]
#define WS_T1   64000    // t1 [500]
#define WS_M    64512    // M  [63][128]
#define WS_B2   72576    // b2 [63]
#define WS_H0   72704    // h0 [128]
#define WS_H1   72832    // h1 [128]
#define WS_H2   72960    // h2 [128]

__device__ __forceinline__ float sigmoidf_(float v) {
    return 1.0f / (1.0f + expf(-v));
}

__device__ __forceinline__ float wave_reduce(float v) {
#pragma unroll
    for (int off = 32; off > 0; off >>= 1)
        v += __shfl_down(v, off, 64);
    return v;
}

// One wave computes h[r]: i,g,o gate dots (K=128, float2/lane) + activation.
// h0=c0=0 -> f gate irrelevant, W_hh contributes nothing.
__device__ __forceinline__ void lstm_row(
    int r, int lane,
    const float* __restrict__ x,    // [H]
    const float* __restrict__ W,    // [4H, H] this layer
    const float* __restrict__ bi,   // [4H]
    const float* __restrict__ bh,   // [4H]
    float* __restrict__ h)          // [H]
{
    const float2 xv = ((const float2*)x)[lane];
    const float2 a = ((const float2*)(W + (size_t)(0 * H + r) * H))[lane];
    const float2 b = ((const float2*)(W + (size_t)(2 * H + r) * H))[lane];
    const float2 c = ((const float2*)(W + (size_t)(3 * H + r) * H))[lane];
    float pi = fmaf(a.x, xv.x, a.y * xv.y);
    float pg = fmaf(b.x, xv.x, b.y * xv.y);
    float po = fmaf(c.x, xv.x, c.y * xv.y);
    pi = wave_reduce(pi);
    pg = wave_reduce(pg);
    po = wave_reduce(po);
    if (lane == 0) {
        const float ig = pi + bi[0 * H + r] + bh[0 * H + r];
        const float gg = pg + bi[2 * H + r] + bh[2 * H + r];
        const float og = po + bi[3 * H + r] + bh[3 * H + r];
        const float cc = sigmoidf_(ig) * tanhf(gg);
        h[r] = sigmoidf_(og) * tanhf(cc);
    }
}

// One wave: y[r] = dot(Wrow, x[K]) + b[r], K multiple of 4, float4 loop.
__device__ __forceinline__ void mv_row(
    int r, int lane,
    const float* __restrict__ Wrow, const float* __restrict__ x,
    float bias, float* __restrict__ y, int K)
{
    const float4* x4 = (const float4*)x;
    const float4* w4 = (const float4*)Wrow;
    const int K4 = K >> 2;
    float acc = 0.f;
    for (int k = lane; k < K4; k += 64) {
        const float4 a = w4[k];
        const float4 v = x4[k];
        acc = fmaf(a.x, v.x, acc);
        acc = fmaf(a.y, v.y, acc);
        acc = fmaf(a.z, v.z, acc);
        acc = fmaf(a.w, v.w, acc);
    }
    acc = wave_reduce(acc);
    if (lane == 0) y[r] = acc + bias;
}

// K1: blocks [0,32)   : lstm layer 0  -> h0
//     blocks [32,157) : T = W_l1 @ W_fc   [500][128], one wave per row
//     blocks [157,165): t1 = W_l1 @ b_fc + b_l1   [500]
__global__ __launch_bounds__(TPB) void k1(
    const float* __restrict__ x_last,
    const float* __restrict__ W_ih0, const float* __restrict__ b_ih0,
    const float* __restrict__ b_hh0,
    const float* __restrict__ W_fc,  const float* __restrict__ b_fc,
    const float* __restrict__ W_l1,  const float* __restrict__ b_l1,
    float* __restrict__ ws)
{
    const int lane = threadIdx.x & 63;
    const int wv   = threadIdx.x >> 6;
    const int bid  = blockIdx.x;

    if (bid < 32) {
        lstm_row(bid * 4 + wv, lane, x_last, W_ih0, b_ih0, b_hh0, ws + WS_H0);
    } else if (bid < 157) {
        // T[r][c] = sum_k W_l1[r][k] * W_fc[k][c]; lane owns cols (2l, 2l+1)
        const int r = (bid - 32) * 4 + wv;            // [0,500)
        const float* wrow = W_l1 + (size_t)r * FCN;
        const float2* fc2 = (const float2*)W_fc;
        float2 acc = make_float2(0.f, 0.f);
        int k0 = 0;
#pragma unroll 1
        for (int kb = 0; kb < 6; ++kb, k0 += 64) {    // 6*64 = 384
            const float wl = wrow[k0 + lane];
#pragma unroll 16
            for (int b = 0; b < 64; ++b) {
                const float w = __shfl(wl, b, 64);
                const float2 f = fc2[(size_t)(k0 + b) * (H / 2) + lane];
                acc.x = fmaf(w, f.x, acc.x);
                acc.y = fmaf(w, f.y, acc.y);
            }
        }
        {   // tail: k = 384..399
            const float wl = (lane < 16) ? wrow[384 + lane] : 0.f;
#pragma unroll 16
            for (int b = 0; b < 16; ++b) {
                const float w = __shfl(wl, b, 64);
                const float2 f = fc2[(size_t)(384 + b) * (H / 2) + lane];
                acc.x = fmaf(w, f.x, acc.x);
                acc.y = fmaf(w, f.y, acc.y);
            }
        }
        ((float2*)(ws + WS_T + (size_t)r * H))[lane] = acc;
    } else {
        const int gw = (bid - 157) * 4 + wv;          // [0,32)
        for (int r = gw; r < L1N; r += 32)
            mv_row(r, lane, W_l1 + (size_t)r * FCN, b_fc, b_l1[r],
                   ws + WS_T1, FCN);
    }
}

// K2: blocks [0,32)  : lstm layer 1 (h0 -> h1)
//     blocks [32,48) : M = W_l2 @ T   [63][128], one wave per row
//     block  48      : b2 = W_l2 @ t1 + b_l2   [63]
__global__ __launch_bounds__(TPB) void k2(
    const float* __restrict__ W_ih1, const float* __restrict__ b_ih1,
    const float* __restrict__ b_hh1,
    const float* __restrict__ W_l2,  const float* __restrict__ b_l2,
    float* __restrict__ ws)
{
    const int lane = threadIdx.x & 63;
    const int wv   = threadIdx.x >> 6;
    const int bid  = blockIdx.x;

    if (bid < 32) {
        lstm_row(bid * 4 + wv, lane, ws + WS_H0, W_ih1, b_ih1, b_hh1, ws + WS_H1);
    } else if (bid < 48) {
        const int r = (bid - 32) * 4 + wv;            // [0,64)
        if (r < L2N) {
            const float* wrow = W_l2 + (size_t)r * L1N;
            const float2* t2 = (const float2*)(ws + WS_T);
            float2 acc = make_float2(0.f, 0.f);
            int k0 = 0;
#pragma unroll 1
            for (int kb = 0; kb < 7; ++kb, k0 += 64) { // 7*64 = 448
                const float wl = wrow[k0 + lane];
#pragma unroll 16
                for (int b = 0; b < 64; ++b) {
                    const float w = __shfl(wl, b, 64);
                    const float2 f = t2[(size_t)(k0 + b) * (H / 2) + lane];
                    acc.x = fmaf(w, f.x, acc.x);
                    acc.y = fmaf(w, f.y, acc.y);
                }
            }
            {   // tail: k = 448..499
                const float wl = (lane < 52) ? wrow[448 + lane] : 0.f;
#pragma unroll 13
                for (int b = 0; b < 52; ++b) {
                    const float w = __shfl(wl, b, 64);
                    const float2 f = t2[(size_t)(448 + b) * (H / 2) + lane];
                    acc.x = fmaf(w, f.x, acc.x);
                    acc.y = fmaf(w, f.y, acc.y);
                }
            }
            ((float2*)(ws + WS_M + (size_t)r * H))[lane] = acc;
        }
    } else {
        for (int r = wv; r < L2N; r += 4)
            mv_row(r, lane, W_l2 + (size_t)r * L1N, ws + WS_T1, b_l2[r],
                   ws + WS_B2, L1N);
    }
}

// K3: lstm layer 2 (h1 -> h2), 32 blocks
__global__ __launch_bounds__(TPB) void k3(
    const float* __restrict__ W_ih2, const float* __restrict__ b_ih2,
    const float* __restrict__ b_hh2,
    float* __restrict__ ws)
{
    const int lane = threadIdx.x & 63;
    const int wv   = threadIdx.x >> 6;
    lstm_row(blockIdx.x * 4 + wv, lane, ws + WS_H1, W_ih2, b_ih2, b_hh2,
             ws + WS_H2);
}

// K4: out = M @ h2 + b2, one wave per row (K=128, float2/lane), 16 blocks
__global__ __launch_bounds__(TPB) void k4(
    float* __restrict__ out, const float* __restrict__ ws)
{
    const int lane = threadIdx.x & 63;
    const int r = blockIdx.x * 4 + (threadIdx.x >> 6);
    if (r >= L2N) return;
    const float2 xv = ((const float2*)(ws + WS_H2))[lane];
    const float2 wv = ((const float2*)(ws + WS_M + (size_t)r * H))[lane];
    float p = fmaf(wv.x, xv.x, wv.y * xv.y);
    p = wave_reduce(p);
    if (lane == 0) out[r] = p + ws[WS_B2 + r];
}

extern "C" void kernel_launch(void* const* d_in, const int* in_sizes, int n_in,
                              void* d_out, int out_size, void* d_ws, size_t ws_size,
                              hipStream_t stream) {
    const float* inputs = (const float*)d_in[0];
    const float* W_ih   = (const float*)d_in[1];
    // d_in[2] = W_hh (unused: h0 = 0)
    const float* b_ih   = (const float*)d_in[3];
    const float* b_hh   = (const float*)d_in[4];
    const float* W_fc   = (const float*)d_in[5];
    const float* b_fc   = (const float*)d_in[6];
    const float* W_l1   = (const float*)d_in[7];
    const float* b_l1   = (const float*)d_in[8];
    const float* W_l2   = (const float*)d_in[9];
    const float* b_l2   = (const float*)d_in[10];
    float* out = (float*)d_out;
    float* ws  = (float*)d_ws;

    const float* x_last = inputs + (size_t)(STEPS - 1) * H;

    k1<<<165, TPB, 0, stream>>>(x_last,
                                W_ih, b_ih, b_hh,
                                W_fc, b_fc, W_l1, b_l1, ws);
    k2<<<49, TPB, 0, stream>>>(W_ih + 4 * H * H, b_ih + 4 * H, b_hh + 4 * H,
                               W_l2, b_l2, ws);
    k3<<<32, TPB, 0, stream>>>(W_ih + 8 * H * H, b_ih + 8 * H, b_hh + 8 * H, ws);
    k4<<<16, TPB, 0, stream>>>(out, ws);
}

// Round 7
// 119.043 us; speedup vs baseline: 1.0450x; 1.0450x over previous
//
#include <hip/hip_runtime.h>
#include <math.h>

#define H      128
#define FCN    400
#define L1N    500
#define L2N    63
#define STEPS  65536
#define TPB    256
#define NBLK   64   // 256 waves; 64 blocks on 256 CUs -> co-residency guaranteed

// ws float offsets: counters in [0,128) (5 counters, 64B apart), vectors after
#define WS_H0  128
#define WS_H1  256
#define WS_H2  384
#define WS_FC  512    // 400 floats
#define WS_L1  1024   // 500 floats

__device__ __forceinline__ float sigmoidf_(float v) {
    return 1.0f / (1.0f + expf(-v));
}

__device__ __forceinline__ float wave_reduce(float v) {
#pragma unroll
    for (int off = 32; off > 0; off >>= 1)
        v += __shfl_down(v, off, 64);
    return v;
}

// agent-scope loads/stores for cross-XCD-visible intermediates (skip L1)
__device__ __forceinline__ float ld_agent(const float* p) {
    return __hip_atomic_load(p, __ATOMIC_RELAXED, __HIP_MEMORY_SCOPE_AGENT);
}
__device__ __forceinline__ void st_agent(float* p, float v) {
    __hip_atomic_store(p, v, __ATOMIC_RELAXED, __HIP_MEMORY_SCOPE_AGENT);
}

// Grid barrier: distinct counter per site (zeroed by host memset), no reuse.
// __syncthreads drains vmcnt (so prefetch/stage stores are complete), leader
// does release-add then acquire-spins; counters on separate 64B lines.
__device__ __forceinline__ void gbar(unsigned int* c) {
    __syncthreads();
    if (threadIdx.x == 0) {
        __threadfence();
        __hip_atomic_fetch_add(c, 1u, __ATOMIC_RELEASE, __HIP_MEMORY_SCOPE_AGENT);
        while (__hip_atomic_load(c, __ATOMIC_ACQUIRE, __HIP_MEMORY_SCOPE_AGENT)
               < (unsigned)NBLK) {}
    }
    __syncthreads();
}

__global__ __launch_bounds__(TPB) void fused(
    const float* __restrict__ x_last,
    const float* __restrict__ W_ih, const float* __restrict__ b_ih,
    const float* __restrict__ b_hh,
    const float* __restrict__ W_fc, const float* __restrict__ b_fc,
    const float* __restrict__ W_l1, const float* __restrict__ b_l1,
    const float* __restrict__ W_l2, const float* __restrict__ b_l2,
    float* __restrict__ out, float* __restrict__ ws)
{
    const int lane = threadIdx.x & 63;
    const int wv   = (blockIdx.x << 2) | (threadIdx.x >> 6);  // 0..255
    unsigned int* ctr = (unsigned int*)ws;
    float* h0   = ws + WS_H0;
    float* h1   = ws + WS_H1;
    float* h2   = ws + WS_H2;
    float* fc_o = ws + WS_FC;
    float* l1_o = ws + WS_L1;

    const bool isL = (wv < 128);        // lstm row r = wv, all 3 layers
    const int  cw  = wv - 128;          // comp-wave index (waves 128..255)
    const bool hasFC = (cw >= 0 && cw < 100);   // 4 FC rows each
    const bool hasL1 = (cw >= 0 && cw < 125);   // 4 L1 rows each
    const bool hasL2 = (cw >= 0 && cw < L2N);   // 1 L2 row each

    // ---------------- prefetch (all global weight reads issue at t=0) -------
    float2 wg[3][3];            // [layer][gate i,g,o], float2 per lane (K=128)
    float  bs[3][3];
    float2 xv = make_float2(0.f, 0.f);
    if (isL) {
        const int r = wv;
#pragma unroll
        for (int l = 0; l < 3; ++l) {
            const float* base = W_ih + (size_t)l * 4 * H * H;
            wg[l][0] = ((const float2*)(base + (size_t)(0 * H + r) * H))[lane];
            wg[l][1] = ((const float2*)(base + (size_t)(2 * H + r) * H))[lane];
            wg[l][2] = ((const float2*)(base + (size_t)(3 * H + r) * H))[lane];
            bs[l][0] = b_ih[l * 4 * H + 0 * H + r] + b_hh[l * 4 * H + 0 * H + r];
            bs[l][1] = b_ih[l * 4 * H + 2 * H + r] + b_hh[l * 4 * H + 2 * H + r];
            bs[l][2] = b_ih[l * 4 * H + 3 * H + r] + b_hh[l * 4 * H + 3 * H + r];
        }
        xv = ((const float2*)x_last)[lane];
    }

    float2 wfc[4]; float bfc[4];
    if (hasFC) {
#pragma unroll
        for (int j = 0; j < 4; ++j) {
            const int r = cw * 4 + j;                 // < 400
            wfc[j] = ((const float2*)(W_fc + (size_t)r * H))[lane];
            bfc[j] = b_fc[r];
        }
    }

    float w1[4][7]; float b1v[4];                     // L1: K=400 = 6*64 + 16
    if (hasL1) {
#pragma unroll
        for (int j = 0; j < 4; ++j) {
            const int r = cw * 4 + j;                 // < 500
            const float* row = W_l1 + (size_t)r * FCN;
#pragma unroll
            for (int k = 0; k < 6; ++k) w1[j][k] = row[k * 64 + lane];
            w1[j][6] = (lane < 16) ? row[384 + lane] : 0.f;
            b1v[j] = b_l1[r];
        }
    }

    float w2[8]; float b2v = 0.f;                     // L2: K=500 = 7*64 + 52
    if (hasL2) {
        const float* row = W_l2 + (size_t)cw * L1N;
#pragma unroll
        for (int k = 0; k < 7; ++k) w2[k] = row[k * 64 + lane];
        w2[7] = (lane < 52) ? row[448 + lane] : 0.f;
        b2v = b_l2[cw];
    }

    // ---------------- lstm0 ----------------
    if (isL) {
        float pi = fmaf(wg[0][0].x, xv.x, wg[0][0].y * xv.y);
        float pg = fmaf(wg[0][1].x, xv.x, wg[0][1].y * xv.y);
        float po = fmaf(wg[0][2].x, xv.x, wg[0][2].y * xv.y);
        pi = wave_reduce(pi); pg = wave_reduce(pg); po = wave_reduce(po);
        if (lane == 0) {
            const float cc = sigmoidf_(pi + bs[0][0]) * tanhf(pg + bs[0][1]);
            st_agent(&h0[wv], sigmoidf_(po + bs[0][2]) * tanhf(cc));
        }
    }
    gbar(&ctr[0]);

    // ---------------- lstm1 ----------------
    if (isL) {
        float2 hx;
        hx.x = ld_agent(h0 + 2 * lane);
        hx.y = ld_agent(h0 + 2 * lane + 1);
        float pi = fmaf(wg[1][0].x, hx.x, wg[1][0].y * hx.y);
        float pg = fmaf(wg[1][1].x, hx.x, wg[1][1].y * hx.y);
        float po = fmaf(wg[1][2].x, hx.x, wg[1][2].y * hx.y);
        pi = wave_reduce(pi); pg = wave_reduce(pg); po = wave_reduce(po);
        if (lane == 0) {
            const float cc = sigmoidf_(pi + bs[1][0]) * tanhf(pg + bs[1][1]);
            st_agent(&h1[wv], sigmoidf_(po + bs[1][2]) * tanhf(cc));
        }
    }
    gbar(&ctr[16]);

    // ---------------- lstm2 ----------------
    if (isL) {
        float2 hx;
        hx.x = ld_agent(h1 + 2 * lane);
        hx.y = ld_agent(h1 + 2 * lane + 1);
        float pi = fmaf(wg[2][0].x, hx.x, wg[2][0].y * hx.y);
        float pg = fmaf(wg[2][1].x, hx.x, wg[2][1].y * hx.y);
        float po = fmaf(wg[2][2].x, hx.x, wg[2][2].y * hx.y);
        pi = wave_reduce(pi); pg = wave_reduce(pg); po = wave_reduce(po);
        if (lane == 0) {
            const float cc = sigmoidf_(pi + bs[2][0]) * tanhf(pg + bs[2][1]);
            st_agent(&h2[wv], sigmoidf_(po + bs[2][2]) * tanhf(cc));
        }
    }
    gbar(&ctr[32]);

    // ---------------- FC (400 rows, K=128) ----------------
    if (hasFC) {
        float2 hx;
        hx.x = ld_agent(h2 + 2 * lane);
        hx.y = ld_agent(h2 + 2 * lane + 1);
#pragma unroll
        for (int j = 0; j < 4; ++j) {
            float p = fmaf(wfc[j].x, hx.x, wfc[j].y * hx.y);
            p = wave_reduce(p);
            if (lane == 0) st_agent(&fc_o[cw * 4 + j], p + bfc[j]);
        }
    }
    gbar(&ctr[48]);

    // ---------------- L1 (500 rows, K=400) ----------------
    if (hasL1) {
        float xr[7];
#pragma unroll
        for (int k = 0; k < 6; ++k) xr[k] = ld_agent(fc_o + k * 64 + lane);
        xr[6] = (lane < 16) ? ld_agent(fc_o + 384 + lane) : 0.f;
#pragma unroll
        for (int j = 0; j < 4; ++j) {
            float acc = 0.f;
#pragma unroll
            for (int k = 0; k < 7; ++k) acc = fmaf(w1[j][k], xr[k], acc);
            acc = wave_reduce(acc);
            if (lane == 0) st_agent(&l1_o[cw * 4 + j], acc + b1v[j]);
        }
    }
    gbar(&ctr[64]);

    // ---------------- L2 (63 rows, K=500) -> out ----------------
    if (hasL2) {
        float xr[8];
#pragma unroll
        for (int k = 0; k < 7; ++k) xr[k] = ld_agent(l1_o + k * 64 + lane);
        xr[7] = (lane < 52) ? ld_agent(l1_o + 448 + lane) : 0.f;
        float acc = 0.f;
#pragma unroll
        for (int k = 0; k < 8; ++k) acc = fmaf(w2[k], xr[k], acc);
        acc = wave_reduce(acc);
        if (lane == 0) out[cw] = acc + b2v;
    }
}

extern "C" void kernel_launch(void* const* d_in, const int* in_sizes, int n_in,
                              void* d_out, int out_size, void* d_ws, size_t ws_size,
                              hipStream_t stream) {
    const float* inputs = (const float*)d_in[0];
    const float* W_ih   = (const float*)d_in[1];
    // d_in[2] = W_hh (unused: h0 = 0)
    const float* b_ih   = (const float*)d_in[3];
    const float* b_hh   = (const float*)d_in[4];
    const float* W_fc   = (const float*)d_in[5];
    const float* b_fc   = (const float*)d_in[6];
    const float* W_l1   = (const float*)d_in[7];
    const float* b_l1   = (const float*)d_in[8];
    const float* W_l2   = (const float*)d_in[9];
    const float* b_l2   = (const float*)d_in[10];
    float* out = (float*)d_out;
    float* ws  = (float*)d_ws;

    const float* x_last = inputs + (size_t)(STEPS - 1) * H;

    // Zero the 5 barrier counters (64B-spaced in ws[0..128)).
    hipMemsetAsync(ws, 0, 512, stream);

    fused<<<NBLK, TPB, 0, stream>>>(x_last, W_ih, b_ih, b_hh,
                                    W_fc, b_fc, W_l1, b_l1, W_l2, b_l2,
                                    out, ws);
}